// Round 1
// baseline (128.929 us; speedup 1.0000x reference)
//
#include <hip/hip_runtime.h>
#include <hip/hip_bf16.h>

// Problem: B=32, L=512, D=1024, R=128
//   t = batch(16384x1024) @ proj(1024x128)          [bf16 MFMA, fp32 acc]
//   d[b,i,j] = ||t_i||^2 + ||t_j||^2 - 2 t_i.t_j,  clamp >= 0
//
// ws layout: projT bf16 [128][1024] (256KB) | t bf16 [16384][128] (4MB) | sqn f32 [16384] (64KB)

typedef __attribute__((ext_vector_type(8))) short bf16x8;
typedef __attribute__((ext_vector_type(4))) float f32x4;

__device__ __forceinline__ unsigned short f2bf(float f) {
    unsigned u = __float_as_uint(f);
    unsigned r = (u + 0x7fffu + ((u >> 16) & 1u)) >> 16;   // RNE
    return (unsigned short)r;
}
__device__ __forceinline__ float bf2f(unsigned short h) {
    return __uint_as_float(((unsigned)h) << 16);
}
__device__ __forceinline__ bf16x8 pack8(float4 x, float4 y) {
    bf16x8 r;
    r[0] = (short)f2bf(x.x); r[1] = (short)f2bf(x.y);
    r[2] = (short)f2bf(x.z); r[3] = (short)f2bf(x.w);
    r[4] = (short)f2bf(y.x); r[5] = (short)f2bf(y.y);
    r[6] = (short)f2bf(y.z); r[7] = (short)f2bf(y.w);
    return r;
}

// ---------------- kernel 0: proj (1024x128 f32) -> projT (128x1024 bf16) ----------------
__global__ __launch_bounds__(256) void transpose_proj(const float* __restrict__ proj,
                                                      unsigned short* __restrict__ projT) {
    __shared__ unsigned short TsT[128][40];   // [r][k_local], pad 32->40 (80B rows, 16B-aligned)
    const int k0 = blockIdx.x * 32;           // 32 blocks cover D=1024
    const int t = threadIdx.x;
    // load 32 k-rows x 128 r, coalesced float4
    const int kl = t >> 3;                    // 0..31
    const int seg = t & 7;                    // 0..7 -> cols seg*16..seg*16+16
    const float* src = proj + (k0 + kl) * 128 + seg * 16;
#pragma unroll
    for (int i = 0; i < 4; ++i) {
        float4 v = *(const float4*)(src + 4 * i);
        int c = seg * 16 + 4 * i;
        TsT[c + 0][kl] = f2bf(v.x);
        TsT[c + 1][kl] = f2bf(v.y);
        TsT[c + 2][kl] = f2bf(v.z);
        TsT[c + 3][kl] = f2bf(v.w);
    }
    __syncthreads();
    // write projT rows: thread -> r=t>>1, h=t&1, 16 bf16 each
    const int r = t >> 1, h = t & 1;
#pragma unroll
    for (int i = 0; i < 2; ++i) {
        *(uint4*)(projT + r * 1024 + k0 + h * 16 + 8 * i) =
            *(const uint4*)&TsT[r][h * 16 + 8 * i];
    }
}

// ---------------- kernel 1: t = batch @ proj  (M=16384, N=128, K=1024) ----------------
// grid 512 (M-tile 32), block 256 = 4 waves arranged 2(M) x 2(N).
// A fragments straight from global fp32 (each element read exactly once, 128B/row segments),
// projT staged in LDS per 64-wide K chunk.
__global__ __launch_bounds__(256) void gemm_t(const float* __restrict__ batch,
                                              const unsigned short* __restrict__ projT,
                                              unsigned short* __restrict__ tOut,
                                              float* __restrict__ sqn) {
    __shared__ unsigned short Bs[128][72];    // [n][k_local], 144B rows: 2-way banks (free)
    __shared__ float sqpart[2][2][16];

    const int t = threadIdx.x;
    const int wave = t >> 6, lane = t & 63;
    const int wm = wave >> 1, wn = wave & 1;
    const int quad = lane >> 4, l15 = lane & 15;
    const int m0 = blockIdx.x * 32;

    f32x4 acc[4] = {};                        // cols wn*64 + fn*16 .. +16

    const float* aptr = batch + (m0 + wm * 16 + l15) * 1024 + quad * 8;
    const int br = t >> 1, bh = t & 1;        // Bs staging map
    const uint4* bsrc0 = (const uint4*)(projT + br * 1024 + bh * 32);

    for (int kk = 0; kk < 1024; kk += 64) {
        // global loads for this iteration (B stage + both A k-halves)
        const uint4* bsrc = (const uint4*)((const unsigned short*)bsrc0 + kk);
        uint4 b0 = bsrc[0], b1 = bsrc[1], b2 = bsrc[2], b3 = bsrc[3];
        float4 a0 = *(const float4*)(aptr + kk);
        float4 a1 = *(const float4*)(aptr + kk + 4);
        float4 a2 = *(const float4*)(aptr + kk + 32);
        float4 a3 = *(const float4*)(aptr + kk + 36);
        __syncthreads();                      // previous iter's Bs reads complete
        *(uint4*)&Bs[br][bh * 32 + 0]  = b0;
        *(uint4*)&Bs[br][bh * 32 + 8]  = b1;
        *(uint4*)&Bs[br][bh * 32 + 16] = b2;
        *(uint4*)&Bs[br][bh * 32 + 24] = b3;
        __syncthreads();

        bf16x8 af0 = pack8(a0, a1);
        bf16x8 af1 = pack8(a2, a3);
#pragma unroll
        for (int fn = 0; fn < 4; ++fn) {
            bf16x8 bf_ = *(const bf16x8*)&Bs[wn * 64 + fn * 16 + l15][quad * 8];
            acc[fn] = __builtin_amdgcn_mfma_f32_16x16x32_bf16(af0, bf_, acc[fn], 0, 0, 0);
        }
#pragma unroll
        for (int fn = 0; fn < 4; ++fn) {
            bf16x8 bf_ = *(const bf16x8*)&Bs[wn * 64 + fn * 16 + l15][32 + quad * 8];
            acc[fn] = __builtin_amdgcn_mfma_f32_16x16x32_bf16(af1, bf_, acc[fn], 0, 0, 0);
        }
    }

    // epilogue: write t (bf16), accumulate row sq-norms from the ROUNDED values
    float p[4] = {0.f, 0.f, 0.f, 0.f};
#pragma unroll
    for (int fn = 0; fn < 4; ++fn) {
        int col = wn * 64 + fn * 16 + l15;
#pragma unroll
        for (int reg = 0; reg < 4; ++reg) {
            int row = m0 + wm * 16 + quad * 4 + reg;
            unsigned short hb = f2bf(acc[fn][reg]);
            tOut[row * 128 + col] = hb;
            float fv = bf2f(hb);
            p[reg] += fv * fv;
        }
    }
#pragma unroll
    for (int off = 1; off < 16; off <<= 1) {
#pragma unroll
        for (int reg = 0; reg < 4; ++reg) p[reg] += __shfl_xor(p[reg], off);
    }
    if (l15 == 0) {
#pragma unroll
        for (int reg = 0; reg < 4; ++reg) sqpart[wm][wn][quad * 4 + reg] = p[reg];
    }
    __syncthreads();
    if (t < 32) {
        int wmi = t >> 4, ridx = t & 15;
        sqn[m0 + wmi * 16 + ridx] = sqpart[wmi][0][ridx] + sqpart[wmi][1][ridx];
    }
}

// ---------------- kernel 2: d[b,i,j] = sq_i + sq_j - 2 * t_i . t_j, clamped ----------------
// grid 512 = 32 batches x (4 i-tiles x 4 j-tiles of 128). block 256 = 4 waves, wave owns 32 i-rows.
__global__ __launch_bounds__(256) void dist_k(const unsigned short* __restrict__ tMat,
                                              const float* __restrict__ sqn,
                                              float* __restrict__ out) {
    __shared__ unsigned short Tj[128][136];   // 272B rows, 16B-aligned, 2-way banks
    __shared__ float sqis[128], sqjs[128];

    const int bx = blockIdx.x;
    const int b = bx >> 4, it = (bx >> 2) & 3, jt = bx & 3;
    const int i0 = it * 128, j0 = jt * 128;
    const int t = threadIdx.x;
    const int wave = t >> 6, lane = t & 63;
    const int quad = lane >> 4, l15 = lane & 15;

    // prefetch this wave's A fragments straight from global t (no cross-wave reuse)
    const unsigned short* abase = tMat + (b * 512 + i0 + wave * 32 + l15) * 128 + quad * 8;
    uint4 araw[2][4];
#pragma unroll
    for (int fm = 0; fm < 2; ++fm)
#pragma unroll
        for (int ksi = 0; ksi < 4; ++ksi)
            araw[fm][ksi] = *(const uint4*)(abase + fm * 16 * 128 + ksi * 32);

    // stage Tj (reused by all 4 waves)
    {
        const int r = t >> 1, h = t & 1;
        const uint4* jsrc = (const uint4*)(tMat + (b * 512 + j0 + r) * 128 + h * 64);
#pragma unroll
        for (int i = 0; i < 8; ++i)
            *(uint4*)&Tj[r][h * 64 + 8 * i] = jsrc[i];
    }
    if (t < 128) sqis[t] = sqn[b * 512 + i0 + t];
    else         sqjs[t - 128] = sqn[b * 512 + j0 + (t - 128)];
    __syncthreads();

    f32x4 acc[2][8] = {};
#pragma unroll
    for (int ksi = 0; ksi < 4; ++ksi) {
        bf16x8 bfr[8];
#pragma unroll
        for (int fn = 0; fn < 8; ++fn)
            bfr[fn] = *(const bf16x8*)&Tj[fn * 16 + l15][ksi * 32 + quad * 8];
#pragma unroll
        for (int fm = 0; fm < 2; ++fm) {
            bf16x8 af = *(const bf16x8*)&araw[fm][ksi];
#pragma unroll
            for (int fn = 0; fn < 8; ++fn)
                acc[fm][fn] = __builtin_amdgcn_mfma_f32_16x16x32_bf16(af, bfr[fn], acc[fm][fn], 0, 0, 0);
        }
    }

    float* obase = out + (size_t)b * 512 * 512;
#pragma unroll
    for (int fm = 0; fm < 2; ++fm) {
#pragma unroll
        for (int reg = 0; reg < 4; ++reg) {
            int il = wave * 32 + fm * 16 + quad * 4 + reg;
            float si = sqis[il];
#pragma unroll
            for (int fn = 0; fn < 8; ++fn) {
                int jl = fn * 16 + l15;
                float v = si + sqjs[jl] - 2.0f * acc[fm][fn][reg];
                obase[(size_t)(i0 + il) * 512 + (j0 + jl)] = fmaxf(v, 0.0f);
            }
        }
    }
}

extern "C" void kernel_launch(void* const* d_in, const int* in_sizes, int n_in,
                              void* d_out, int out_size, void* d_ws, size_t ws_size,
                              hipStream_t stream) {
    (void)in_sizes; (void)n_in; (void)out_size; (void)ws_size;
    const float* batch = (const float*)d_in[0];
    const float* proj  = (const float*)d_in[1];
    float* out = (float*)d_out;

    unsigned short* projT = (unsigned short*)d_ws;          // 128*1024 bf16
    unsigned short* tMat  = projT + 128 * 1024;             // 16384*128 bf16
    float* sqn = (float*)(tMat + 16384 * 128);              // 16384 f32

    hipLaunchKernelGGL(transpose_proj, dim3(32),  dim3(256), 0, stream, proj, projT);
    hipLaunchKernelGGL(gemm_t,         dim3(512), dim3(256), 0, stream, batch, projT, tMat, sqn);
    hipLaunchKernelGGL(dist_k,         dim3(512), dim3(256), 0, stream, tMat, sqn, out);
}